// Round 3
// baseline (203.781 us; speedup 1.0000x reference)
//
#include <hip/hip_runtime.h>
#include <hip/hip_bf16.h>

#define DDIM 448

typedef __hip_bfloat16 bf16;
typedef __attribute__((ext_vector_type(8))) short short8;   // 8 bf16 = 16B (MFMA A/B frag)
typedef __attribute__((ext_vector_type(4))) float f32x4;    // MFMA C/D frag / float4

__device__ __forceinline__ short bf_bits(float f) {
    bf16 h = __float2bfloat16(f);
    return *reinterpret_cast<short*>(&h);
}

// ---------------------------------------------------------------------------
// Kernel 1 (fp32 in, bf16 out):
// W_cT[o][i] = sum_d (Wq[i][d]*A[d][d] + Wk[i][d]*B[d][d] + Wv[i][d]*C[d][d]) * Wo[d][o]
// Stored TRANSPOSED (o-major) so the GEMM's B-fragments are k-contiguous.
// 56 blocks x 448 threads; block handles 8 rows i.
// ---------------------------------------------------------------------------
__global__ __launch_bounds__(448) void prep_wc(
    const float* __restrict__ Wq, const float* __restrict__ Wk,
    const float* __restrict__ Wv, const float* __restrict__ Wo,
    const float* __restrict__ Ad, const float* __restrict__ Bd,
    const float* __restrict__ Cd, bf16* __restrict__ WcT)
{
    __shared__ float weff[8][DDIM];
    const int tid = threadIdx.x;            // 0..447
    const int i0  = blockIdx.x * 8;

    {   // thread tid owns column d = tid of the 8 W_eff rows
        const int d = tid;
        const float a = Ad[d * DDIM + d];
        const float b = Bd[d * DDIM + d];
        const float c = Cd[d * DDIM + d];
        #pragma unroll
        for (int r = 0; r < 8; ++r) {
            const int i = i0 + r;
            weff[r][d] = Wq[i * DDIM + d] * a
                       + Wk[i * DDIM + d] * b
                       + Wv[i * DDIM + d] * c;
        }
    }
    __syncthreads();

    const int o = tid;
    float acc[8] = {0.f,0.f,0.f,0.f,0.f,0.f,0.f,0.f};
    for (int d = 0; d < DDIM; ++d) {
        const float wo = Wo[d * DDIM + o];            // coalesced across o
        #pragma unroll
        for (int r = 0; r < 8; ++r) acc[r] += weff[r][d] * wo;  // weff broadcast
    }

    // pack 8 consecutive i-values -> one 16B store at WcT[o][i0]
    short8 pk;
    #pragma unroll
    for (int r = 0; r < 8; ++r) pk[r] = bf_bits(acc[r]);
    *reinterpret_cast<short8*>(&WcT[o * DDIM + i0]) = pk;
}

// ---------------------------------------------------------------------------
// Kernel 2: out[M x 448](fp32) = X[M x 448](fp32) @ Wc   (WcT bf16, o-major)
// Tile BM=128, BN=64, BK=32. 256 threads = 4 waves (2x2), each wave a 64x32
// sub-tile = 4x2 MFMA 16x16x32 bf16 frags. A staged as fp32 float4 loads ->
// packed cvt to bf16 -> ds_write_b128. Register prefetch of iter k+1 issued
// after barrier 2 overlaps load latency with frag reads + MFMAs.
// ---------------------------------------------------------------------------
__global__ __launch_bounds__(256) void gemm_xwc(
    const float* __restrict__ X, const bf16* __restrict__ WcT,
    float* __restrict__ out)
{
    __shared__ __align__(16) bf16  As[128 * 32];   // row-major, stride 32 (k contig)
    __shared__ __align__(16) bf16  Bs[64 * 32];    // n-major,  stride 32 (k contig)
    __shared__ __align__(16) float Cs[128 * 64];   // epilogue bounce (fp32)

    const int tid  = threadIdx.x;
    const int lane = tid & 63;
    const int wid  = tid >> 6;      // 0..3
    const int wm   = wid >> 1;      // 0..1 : row half
    const int wn   = wid & 1;       // 0..1 : col half

    const int row0 = blockIdx.y * 128;
    const int col0 = blockIdx.x * 64;

    // A staging: 128x32 fp32 -> 16 elems (4 float4) per thread
    const int ar = tid >> 1;               // 0..127
    const int ac = (tid & 1) * 16;         // 0 or 16
    const float* agp = X + (row0 + ar) * DDIM + ac;
    // B staging: 64x32 bf16 -> 1 short8 per thread
    const int br = tid >> 2;               // 0..63
    const int bc = (tid & 3) * 8;
    const bf16* bgp = WcT + (col0 + br) * DDIM + bc;

    const int m_ = lane & 15;
    const int kq = lane >> 4;              // k-quadrant: covers k = kq*8..kq*8+7

    f32x4 acc[4][2] = {};

    // prologue prefetch (k0 = 0)
    f32x4 a0 = *reinterpret_cast<const f32x4*>(agp);
    f32x4 a1 = *reinterpret_cast<const f32x4*>(agp + 4);
    f32x4 a2 = *reinterpret_cast<const f32x4*>(agp + 8);
    f32x4 a3 = *reinterpret_cast<const f32x4*>(agp + 12);
    short8 b0 = *reinterpret_cast<const short8*>(bgp);

    for (int k0 = 0; k0 < DDIM; k0 += 32) {
        __syncthreads();   // prior iteration's frag ds_reads drained
        short8 w0, w1;
        #pragma unroll
        for (int j = 0; j < 4; ++j) {
            w0[j]     = bf_bits(a0[j]);
            w0[j + 4] = bf_bits(a1[j]);
            w1[j]     = bf_bits(a2[j]);
            w1[j + 4] = bf_bits(a3[j]);
        }
        *reinterpret_cast<short8*>(&As[ar * 32 + ac])     = w0;
        *reinterpret_cast<short8*>(&As[ar * 32 + ac + 8]) = w1;
        *reinterpret_cast<short8*>(&Bs[br * 32 + bc])     = b0;
        __syncthreads();

        // prefetch next K-tile (dummy re-read of k=0 on last iter; discarded)
        const int kn = (k0 + 32 < DDIM) ? k0 + 32 : 0;
        a0 = *reinterpret_cast<const f32x4*>(agp + kn);
        a1 = *reinterpret_cast<const f32x4*>(agp + kn + 4);
        a2 = *reinterpret_cast<const f32x4*>(agp + kn + 8);
        a3 = *reinterpret_cast<const f32x4*>(agp + kn + 12);
        b0 = *reinterpret_cast<const short8*>(bgp + kn);

        short8 af[4], bfr[2];
        #pragma unroll
        for (int mi = 0; mi < 4; ++mi)
            af[mi] = *reinterpret_cast<const short8*>(
                &As[(wm * 64 + mi * 16 + m_) * 32 + kq * 8]);
        #pragma unroll
        for (int ni = 0; ni < 2; ++ni)
            bfr[ni] = *reinterpret_cast<const short8*>(
                &Bs[(wn * 32 + ni * 16 + m_) * 32 + kq * 8]);

        #pragma unroll
        for (int mi = 0; mi < 4; ++mi)
            #pragma unroll
            for (int ni = 0; ni < 2; ++ni)
                acc[mi][ni] = __builtin_amdgcn_mfma_f32_16x16x32_bf16(
                    af[mi], bfr[ni], acc[mi][ni], 0, 0, 0);
    }

    // ---- epilogue: frags -> Cs (fp32) -> coalesced 16B global stores ----
    __syncthreads();
    #pragma unroll
    for (int mi = 0; mi < 4; ++mi) {
        #pragma unroll
        for (int ni = 0; ni < 2; ++ni) {
            const int col = wn * 32 + ni * 16 + m_;        // C col = lane&15  [m89]
            const int rb  = wm * 64 + mi * 16 + kq * 4;    // C row = quad*4+reg
            #pragma unroll
            for (int r = 0; r < 4; ++r)
                Cs[(rb + r) * 64 + col] = acc[mi][ni][r];
        }
    }
    __syncthreads();

    // 128 rows x 64 fp32 cols: 16 threads/row x 16B, 8 rounds of 16 rows
    #pragma unroll
    for (int rr = 0; rr < 8; ++rr) {
        const int r    = rr * 16 + (tid >> 4);
        const int cseg = (tid & 15) * 4;
        f32x4 v = *reinterpret_cast<const f32x4*>(&Cs[r * 64 + cseg]);
        *reinterpret_cast<f32x4*>(&out[(row0 + r) * DDIM + col0 + cseg]) = v;
    }
}

// ---------------------------------------------------------------------------
extern "C" void kernel_launch(void* const* d_in, const int* in_sizes, int n_in,
                              void* d_out, int out_size, void* d_ws, size_t ws_size,
                              hipStream_t stream) {
    const float* x  = (const float*)d_in[0];
    const float* Wq = (const float*)d_in[1];
    const float* Wk = (const float*)d_in[2];
    const float* Wv = (const float*)d_in[3];
    const float* Wo = (const float*)d_in[4];
    const float* Ad = (const float*)d_in[5];
    const float* Bd = (const float*)d_in[6];
    const float* Cd = (const float*)d_in[7];

    bf16*  WcT = (bf16*)d_ws;                      // 448*448*2 = 392 KiB scratch
    float* out = (float*)d_out;

    const int M = in_sizes[0] / DDIM;              // 8*4096 = 32768

    prep_wc<<<DDIM / 8, DDIM, 0, stream>>>(Wq, Wk, Wv, Wo, Ad, Bd, Cd, WcT);

    dim3 grid(DDIM / 64, M / 128);                 // 7 x 256 = 1792 blocks
    gemm_xwc<<<grid, 256, 0, stream>>>(x, WcT, out);
}

// Round 4
// 156.251 us; speedup vs baseline: 1.3042x; 1.3042x over previous
//
#include <hip/hip_runtime.h>
#include <hip/hip_bf16.h>

#define DDIM 448

typedef __hip_bfloat16 bf16;
typedef __attribute__((ext_vector_type(8))) short short8;   // 8 bf16 = 16B (MFMA A/B frag)
typedef __attribute__((ext_vector_type(4))) float f32x4;    // MFMA C/D frag / float4

__device__ __forceinline__ short bf_bits(float f) {
    bf16 h = __float2bfloat16(f);
    return *reinterpret_cast<short*>(&h);
}

// async global->LDS DMA: per-lane 16B gather; LDS dst = wave-uniform base + lane*16
__device__ __forceinline__ void async16(const bf16* g, bf16* l) {
    __builtin_amdgcn_global_load_lds(
        (const __attribute__((address_space(1))) void*)g,
        (__attribute__((address_space(3))) void*)l, 16, 0, 0);
}

// ---------------------------------------------------------------------------
// Kernel 1: WcT[o][i] = sum_d Wo[d][o] * E[i][d],
//           E[i][d] = Wq[i][d]*diagA[d] + Wk[i][d]*diagB[d] + Wv[i][d]*diagC[d]
// MFMA GEMM: M=o, N=i, K=d. 49 blocks (7x7) of 64x64, BK=32, 256 thr / 4 waves.
// A-tile = Wo^T staged via LDS transpose; B-tile = E computed during staging.
// ---------------------------------------------------------------------------
__global__ __launch_bounds__(256) void prep_wc(
    const float* __restrict__ Wq, const float* __restrict__ Wk,
    const float* __restrict__ Wv, const float* __restrict__ Wo,
    const float* __restrict__ Ad, const float* __restrict__ Bd,
    const float* __restrict__ Cd, bf16* __restrict__ WcT)
{
    __shared__ __align__(16) bf16 As[64 * 32];   // A[o][d], d contig
    __shared__ __align__(16) bf16 Bs[64 * 32];   // B[i][d], d contig
    __shared__ float da[DDIM], db[DDIM], dc[DDIM];

    const int tid  = threadIdx.x;
    const int i0   = blockIdx.x * 64;
    const int o0   = blockIdx.y * 64;
    const int lane = tid & 63;
    const int wid  = tid >> 6;
    const int wm   = wid >> 1, wn = wid & 1;
    const int m_   = lane & 15, kq = lane >> 4;

    for (int d = tid; d < DDIM; d += 256) {      // diag preload
        da[d] = Ad[d * DDIM + d];
        db[d] = Bd[d * DDIM + d];
        dc[d] = Cd[d * DDIM + d];
    }

    // A staging map: 32 d-rows x 64 o-cols fp32, transposed into As
    const int dr  = tid >> 3;         // 0..31
    const int oc8 = (tid & 7) * 8;    // 0..56
    // B staging map: 64 i-rows x 32 d-cols
    const int ir  = tid >> 2;         // 0..63
    const int dc8 = (tid & 3) * 8;    // 0..24

    f32x4 acc[2][2] = {};

    // prologue prefetch (k0 = 0)
    f32x4 w0 = *(const f32x4*)(Wo + dr * DDIM + o0 + oc8);
    f32x4 w1 = *(const f32x4*)(Wo + dr * DDIM + o0 + oc8 + 4);
    f32x4 q0 = *(const f32x4*)(Wq + (i0 + ir) * DDIM + dc8);
    f32x4 q1 = *(const f32x4*)(Wq + (i0 + ir) * DDIM + dc8 + 4);
    f32x4 t0 = *(const f32x4*)(Wk + (i0 + ir) * DDIM + dc8);
    f32x4 t1 = *(const f32x4*)(Wk + (i0 + ir) * DDIM + dc8 + 4);
    f32x4 v0 = *(const f32x4*)(Wv + (i0 + ir) * DDIM + dc8);
    f32x4 v1 = *(const f32x4*)(Wv + (i0 + ir) * DDIM + dc8 + 4);

    for (int k0 = 0; k0 < DDIM; k0 += 32) {
        __syncthreads();    // prior frag reads done; also publishes diag on iter 0

        // A: transpose-write Wo^T
        #pragma unroll
        for (int j = 0; j < 4; ++j) {
            As[(oc8 + j) * 32 + dr]     = __float2bfloat16(w0[j]);
            As[(oc8 + 4 + j) * 32 + dr] = __float2bfloat16(w1[j]);
        }
        // B: fold diag, write E
        short8 e;
        #pragma unroll
        for (int j = 0; j < 4; ++j) {
            e[j]     = bf_bits(q0[j] * da[k0 + dc8 + j]
                             + t0[j] * db[k0 + dc8 + j]
                             + v0[j] * dc[k0 + dc8 + j]);
            e[j + 4] = bf_bits(q1[j] * da[k0 + dc8 + 4 + j]
                             + t1[j] * db[k0 + dc8 + 4 + j]
                             + v1[j] * dc[k0 + dc8 + 4 + j]);
        }
        *(short8*)&Bs[ir * 32 + dc8] = e;
        __syncthreads();

        // prefetch next K-tile (dummy k=0 re-read on last iter)
        const int kn = (k0 + 32 < DDIM) ? k0 + 32 : 0;
        w0 = *(const f32x4*)(Wo + (kn + dr) * DDIM + o0 + oc8);
        w1 = *(const f32x4*)(Wo + (kn + dr) * DDIM + o0 + oc8 + 4);
        q0 = *(const f32x4*)(Wq + (i0 + ir) * DDIM + kn + dc8);
        q1 = *(const f32x4*)(Wq + (i0 + ir) * DDIM + kn + dc8 + 4);
        t0 = *(const f32x4*)(Wk + (i0 + ir) * DDIM + kn + dc8);
        t1 = *(const f32x4*)(Wk + (i0 + ir) * DDIM + kn + dc8 + 4);
        v0 = *(const f32x4*)(Wv + (i0 + ir) * DDIM + kn + dc8);
        v1 = *(const f32x4*)(Wv + (i0 + ir) * DDIM + kn + dc8 + 4);

        short8 af[2], bfr[2];
        #pragma unroll
        for (int mi = 0; mi < 2; ++mi)
            af[mi] = *(const short8*)&As[(wm * 32 + mi * 16 + m_) * 32 + kq * 8];
        #pragma unroll
        for (int ni = 0; ni < 2; ++ni)
            bfr[ni] = *(const short8*)&Bs[(wn * 32 + ni * 16 + m_) * 32 + kq * 8];
        #pragma unroll
        for (int mi = 0; mi < 2; ++mi)
            #pragma unroll
            for (int ni = 0; ni < 2; ++ni)
                acc[mi][ni] = __builtin_amdgcn_mfma_f32_16x16x32_bf16(
                    af[mi], bfr[ni], acc[mi][ni], 0, 0, 0);
    }

    // epilogue: scalar bf16 stores (tiny kernel)
    #pragma unroll
    for (int mi = 0; mi < 2; ++mi)
        #pragma unroll
        for (int ni = 0; ni < 2; ++ni) {
            const int o = o0 + wm * 32 + mi * 16 + kq * 4;   // + r
            const int i = i0 + wn * 32 + ni * 16 + m_;
            #pragma unroll
            for (int r = 0; r < 4; ++r)
                WcT[(o + r) * DDIM + i] = __float2bfloat16(acc[mi][ni][r]);
        }
}

// ---------------------------------------------------------------------------
// Kernel 2: out[M x 448](fp32) = X(fp32) @ Wc      (WcT bf16, o-major, i contig)
// BM=64, BN=448 (full width -> x read from HBM exactly once), BK=32.
// 256 thr / 4 waves; wave w owns cols [w*112, w*112+112): acc[4][7] frags.
// A: fp32 float4 reg-prefetch -> cvt -> ds_write (single buffer).
// B: global_load_lds 16B DMA into double-buffered Bs (drain overlaps a full step).
// Epilogue: per-16-row LDS bounce -> fully coalesced f32x4 stores.
// ---------------------------------------------------------------------------
__global__ __launch_bounds__(256, 2) void gemm_xwc(
    const float* __restrict__ X, const bf16* __restrict__ WcT,
    float* __restrict__ out)
{
    __shared__ __align__(16) char smem[61440];
    bf16* As  = (bf16*)smem;                 // 64 x 32, 4 KB
    bf16* Bs0 = (bf16*)(smem + 4096);        // 448 x 32, 28 KB
    bf16* Bs1 = (bf16*)(smem + 32768);       // 448 x 32, 28 KB
    float* Cb = (float*)(smem + 4096);       // 16 x 448 fp32 bounce (aliases Bs0)

    const int tid  = threadIdx.x;
    const int lane = tid & 63;
    const int wid  = tid >> 6;               // 0..3 : col quarter (112 cols)
    const int m_   = lane & 15;
    const int kq   = lane >> 4;
    const int row0 = blockIdx.x * 64;

    // A staging: 64x32 fp32 -> 8 elem/thread
    const int ar = tid >> 2;                 // 0..63
    const int ac = (tid & 3) * 8;            // 0,8,16,24
    const float* agp = X + (row0 + ar) * DDIM + ac;

    // B DMA per-lane global addressing (16 rows x 64B per instruction)
    const int lrow = lane >> 2;              // 0..15
    const int lcol = (lane & 3) * 8;         // elements

    f32x4 acc[4][7] = {};

    // prologue: B-DMA(0) + A-regs(0)
    #pragma unroll
    for (int j = 0; j < 7; ++j)
        async16(WcT + ((wid * 7 + j) * 16 + lrow) * DDIM + lcol,
                Bs0 + (wid * 7 + j) * 16 * 32);
    f32x4 a0 = *(const f32x4*)agp;
    f32x4 a1 = *(const f32x4*)(agp + 4);

    int s = 0;
    for (int k0 = 0; k0 < DDIM; k0 += 32, ++s) {
        __syncthreads();                     // (1) prior frag reads drained
        short8 w;
        #pragma unroll
        for (int j = 0; j < 4; ++j) {
            w[j]     = bf_bits(a0[j]);
            w[j + 4] = bf_bits(a1[j]);
        }
        *(short8*)&As[ar * 32 + ac] = w;
        __syncthreads();                     // (2) drains A-writes + B-DMA(s)

        const int kn = k0 + 32;
        if (kn < DDIM) {                     // uniform branch
            bf16* Bnxt = ((s + 1) & 1) ? Bs1 : Bs0;
            #pragma unroll
            for (int j = 0; j < 7; ++j)
                async16(WcT + ((wid * 7 + j) * 16 + lrow) * DDIM + kn + lcol,
                        Bnxt + (wid * 7 + j) * 16 * 32);
            a0 = *(const f32x4*)(agp + kn);
            a1 = *(const f32x4*)(agp + kn + 4);
        }

        const bf16* Bcur = (s & 1) ? Bs1 : Bs0;
        short8 af[4], bfr[7];
        #pragma unroll
        for (int mi = 0; mi < 4; ++mi)
            af[mi] = *(const short8*)&As[(mi * 16 + m_) * 32 + kq * 8];
        #pragma unroll
        for (int ni = 0; ni < 7; ++ni)
            bfr[ni] = *(const short8*)&Bcur[(wid * 112 + ni * 16 + m_) * 32 + kq * 8];

        #pragma unroll
        for (int mi = 0; mi < 4; ++mi)
            #pragma unroll
            for (int ni = 0; ni < 7; ++ni)
                acc[mi][ni] = __builtin_amdgcn_mfma_f32_16x16x32_bf16(
                    af[mi], bfr[ni], acc[mi][ni], 0, 0, 0);
    }

    // ---- epilogue: 4 stages of 16 rows; LDS bounce -> coalesced f32x4 stores
    #pragma unroll
    for (int mi = 0; mi < 4; ++mi) {
        __syncthreads();                     // readers of previous stage done
        #pragma unroll
        for (int ni = 0; ni < 7; ++ni) {
            const int col = wid * 112 + ni * 16 + m_;
            #pragma unroll
            for (int r = 0; r < 4; ++r)
                Cb[(kq * 4 + r) * DDIM + col] = acc[mi][ni][r];
        }
        __syncthreads();
        float* dst = out + (row0 + mi * 16) * DDIM;   // 16x448 tile is contiguous
        #pragma unroll
        for (int j = 0; j < 7; ++j)
            ((f32x4*)dst)[j * 256 + tid] = ((const f32x4*)Cb)[j * 256 + tid];
    }
}

// ---------------------------------------------------------------------------
extern "C" void kernel_launch(void* const* d_in, const int* in_sizes, int n_in,
                              void* d_out, int out_size, void* d_ws, size_t ws_size,
                              hipStream_t stream) {
    const float* x  = (const float*)d_in[0];
    const float* Wq = (const float*)d_in[1];
    const float* Wk = (const float*)d_in[2];
    const float* Wv = (const float*)d_in[3];
    const float* Wo = (const float*)d_in[4];
    const float* Ad = (const float*)d_in[5];
    const float* Bd = (const float*)d_in[6];
    const float* Cd = (const float*)d_in[7];

    bf16*  WcT = (bf16*)d_ws;                      // 448*448*2 = 392 KiB scratch
    float* out = (float*)d_out;

    const int M = in_sizes[0] / DDIM;              // 32768

    prep_wc<<<dim3(7, 7), 256, 0, stream>>>(Wq, Wk, Wv, Wo, Ad, Bd, Cd, WcT);
    gemm_xwc<<<M / 64, 256, 0, stream>>>(x, WcT, out);
}

// Round 6
// 147.566 us; speedup vs baseline: 1.3810x; 1.0589x over previous
//
#include <hip/hip_runtime.h>
#include <hip/hip_bf16.h>

#define DDIM 448
#define NSTEP 14            // 448 / 32

typedef __hip_bfloat16 bf16;
typedef __attribute__((ext_vector_type(8))) short short8;   // 8 bf16 = 16B (MFMA A/B frag)
typedef __attribute__((ext_vector_type(4))) float f32x4;    // MFMA C/D frag / float4

__device__ __forceinline__ short bf_bits(float f) {
    bf16 h = __float2bfloat16(f);
    return *reinterpret_cast<short*>(&h);
}

// async global->LDS DMA: per-lane 16B; LDS dst = wave-uniform base + lane*16
__device__ __forceinline__ void async16(const bf16* g, bf16* l) {
    __builtin_amdgcn_global_load_lds(
        (const __attribute__((address_space(1))) void*)g,
        (__attribute__((address_space(3))) void*)l, 16, 0, 0);
}

// ---------------------------------------------------------------------------
// Kernel 1: WcT[o][i] = sum_d Wo[d][o] * E[i][d],
//           E[i][d] = Wq[i][d]*diagA[d] + Wk[i][d]*diagB[d] + Wv[i][d]*diagC[d]
// (unchanged from R4 — passed, ~5 µs)
// ---------------------------------------------------------------------------
__global__ __launch_bounds__(256) void prep_wc(
    const float* __restrict__ Wq, const float* __restrict__ Wk,
    const float* __restrict__ Wv, const float* __restrict__ Wo,
    const float* __restrict__ Ad, const float* __restrict__ Bd,
    const float* __restrict__ Cd, bf16* __restrict__ WcT)
{
    __shared__ __align__(16) bf16 As[64 * 32];
    __shared__ __align__(16) bf16 Bs[64 * 32];
    __shared__ float da[DDIM], db[DDIM], dc[DDIM];

    const int tid  = threadIdx.x;
    const int i0   = blockIdx.x * 64;
    const int o0   = blockIdx.y * 64;
    const int lane = tid & 63;
    const int wid  = tid >> 6;
    const int wm   = wid >> 1, wn = wid & 1;
    const int m_   = lane & 15, kq = lane >> 4;

    for (int d = tid; d < DDIM; d += 256) {
        da[d] = Ad[d * DDIM + d];
        db[d] = Bd[d * DDIM + d];
        dc[d] = Cd[d * DDIM + d];
    }

    const int dr  = tid >> 3;
    const int oc8 = (tid & 7) * 8;
    const int ir  = tid >> 2;
    const int dc8 = (tid & 3) * 8;

    f32x4 acc[2][2] = {};

    f32x4 w0 = *(const f32x4*)(Wo + dr * DDIM + o0 + oc8);
    f32x4 w1 = *(const f32x4*)(Wo + dr * DDIM + o0 + oc8 + 4);
    f32x4 q0 = *(const f32x4*)(Wq + (i0 + ir) * DDIM + dc8);
    f32x4 q1 = *(const f32x4*)(Wq + (i0 + ir) * DDIM + dc8 + 4);
    f32x4 t0 = *(const f32x4*)(Wk + (i0 + ir) * DDIM + dc8);
    f32x4 t1 = *(const f32x4*)(Wk + (i0 + ir) * DDIM + dc8 + 4);
    f32x4 v0 = *(const f32x4*)(Wv + (i0 + ir) * DDIM + dc8);
    f32x4 v1 = *(const f32x4*)(Wv + (i0 + ir) * DDIM + dc8 + 4);

    for (int k0 = 0; k0 < DDIM; k0 += 32) {
        __syncthreads();
        #pragma unroll
        for (int j = 0; j < 4; ++j) {
            As[(oc8 + j) * 32 + dr]     = __float2bfloat16(w0[j]);
            As[(oc8 + 4 + j) * 32 + dr] = __float2bfloat16(w1[j]);
        }
        short8 e;
        #pragma unroll
        for (int j = 0; j < 4; ++j) {
            e[j]     = bf_bits(q0[j] * da[k0 + dc8 + j]
                             + t0[j] * db[k0 + dc8 + j]
                             + v0[j] * dc[k0 + dc8 + j]);
            e[j + 4] = bf_bits(q1[j] * da[k0 + dc8 + 4 + j]
                             + t1[j] * db[k0 + dc8 + 4 + j]
                             + v1[j] * dc[k0 + dc8 + 4 + j]);
        }
        *(short8*)&Bs[ir * 32 + dc8] = e;
        __syncthreads();

        const int kn = (k0 + 32 < DDIM) ? k0 + 32 : 0;
        w0 = *(const f32x4*)(Wo + (kn + dr) * DDIM + o0 + oc8);
        w1 = *(const f32x4*)(Wo + (kn + dr) * DDIM + o0 + oc8 + 4);
        q0 = *(const f32x4*)(Wq + (i0 + ir) * DDIM + kn + dc8);
        q1 = *(const f32x4*)(Wq + (i0 + ir) * DDIM + kn + dc8 + 4);
        t0 = *(const f32x4*)(Wk + (i0 + ir) * DDIM + kn + dc8);
        t1 = *(const f32x4*)(Wk + (i0 + ir) * DDIM + kn + dc8 + 4);
        v0 = *(const f32x4*)(Wv + (i0 + ir) * DDIM + kn + dc8);
        v1 = *(const f32x4*)(Wv + (i0 + ir) * DDIM + kn + dc8 + 4);

        short8 af[2], bfr[2];
        #pragma unroll
        for (int mi = 0; mi < 2; ++mi)
            af[mi] = *(const short8*)&As[(wm * 32 + mi * 16 + m_) * 32 + kq * 8];
        #pragma unroll
        for (int ni = 0; ni < 2; ++ni)
            bfr[ni] = *(const short8*)&Bs[(wn * 32 + ni * 16 + m_) * 32 + kq * 8];
        #pragma unroll
        for (int mi = 0; mi < 2; ++mi)
            #pragma unroll
            for (int ni = 0; ni < 2; ++ni)
                acc[mi][ni] = __builtin_amdgcn_mfma_f32_16x16x32_bf16(
                    af[mi], bfr[ni], acc[mi][ni], 0, 0, 0);
    }

    #pragma unroll
    for (int mi = 0; mi < 2; ++mi)
        #pragma unroll
        for (int ni = 0; ni < 2; ++ni) {
            const int o = o0 + wm * 32 + mi * 16 + kq * 4;
            const int i = i0 + wn * 32 + ni * 16 + m_;
            #pragma unroll
            for (int r = 0; r < 4; ++r)
                WcT[(o + r) * DDIM + i] = __float2bfloat16(acc[mi][ni][r]);
        }
}

// ---------------------------------------------------------------------------
// Kernel 2: out[M x 448](fp32) = X(fp32) @ Wc    (WcT bf16, o-major, i contig)
// BM=128, BN=448, BK=32. 256 blocks = 1/CU, 4 waves; wave w owns cols
// [w*112, w*112+112): acc[8][7] frags. Both A and B double-buffered;
// ONE barrier per K-step. Buffer selection via byte offsets (no pointer
// arrays — addrspacecast static-init is rejected by gfx950 codegen, R5).
// smem layout: A0 @0 (8K), A1 @8K (8K), B0 @16K (28K), B1 @44K (28K);
// epilogue bounce Cb aliases @16K (56K fp32 for 32x448).
// ---------------------------------------------------------------------------
__global__ __launch_bounds__(256, 1) void gemm_xwc(
    const float* __restrict__ X, const bf16* __restrict__ WcT,
    float* __restrict__ out)
{
    __shared__ __align__(16) char smem[73728];          // 72 KB

    const int tid  = threadIdx.x;
    const int lane = tid & 63;
    const int wid  = tid >> 6;               // col quarter: 112 cols
    const int m_   = lane & 15;
    const int kq   = lane >> 4;
    const int row0 = blockIdx.x * 128;

    // A staging: 128x32 fp32 -> 16 elem/thread
    const int ar = tid >> 1;                 // 0..127
    const int ac = (tid & 1) * 16;           // 0 or 16
    const float* agp = X + (row0 + ar) * DDIM + ac;

    // B DMA lane map: instr j covers rows (wid*7+j)*16 + lrow, 64B per row
    const int lrow = lane >> 2;
    const int lcol = (lane & 3) * 8;
    const bf16* bgp = WcT + (wid * 112 + lrow) * DDIM + lcol;

    f32x4 acc[8][7] = {};

    // ---- prologue: DMA B(0); load+stage A(0); prefetch a-regs for k=32
    {
        bf16* B0 = (bf16*)(smem + 16384);
        #pragma unroll
        for (int j = 0; j < 7; ++j)
            async16(bgp + j * 16 * DDIM, B0 + (wid * 7 + j) * 16 * 32);
    }

    f32x4 a0 = *(const f32x4*)(agp);
    f32x4 a1 = *(const f32x4*)(agp + 4);
    f32x4 a2 = *(const f32x4*)(agp + 8);
    f32x4 a3 = *(const f32x4*)(agp + 12);
    {
        bf16* A0 = (bf16*)smem;
        short8 w0, w1;
        #pragma unroll
        for (int j = 0; j < 4; ++j) {
            w0[j] = bf_bits(a0[j]); w0[j + 4] = bf_bits(a1[j]);
            w1[j] = bf_bits(a2[j]); w1[j + 4] = bf_bits(a3[j]);
        }
        *(short8*)&A0[ar * 32 + ac]     = w0;
        *(short8*)&A0[ar * 32 + ac + 8] = w1;
    }
    a0 = *(const f32x4*)(agp + 32);
    a1 = *(const f32x4*)(agp + 36);
    a2 = *(const f32x4*)(agp + 40);
    a3 = *(const f32x4*)(agp + 44);
    __syncthreads();                          // drains DMA(0), A(0) writes

    for (int s = 0; s < NSTEP; ++s) {
        const int cur = s & 1, nxt = cur ^ 1;
        const bf16* Ac = (const bf16*)(smem + (cur << 13));           // 0 / 8K
        const bf16* Bc = (const bf16*)(smem + 16384 + cur * 28672);   // 16K / 44K

        if (s + 1 < NSTEP) {                  // uniform
            bf16* An = (bf16*)(smem + (nxt << 13));
            bf16* Bn = (bf16*)(smem + 16384 + nxt * 28672);
            // stage A(next) from regs (hold k=(s+1)*32)
            short8 w0, w1;
            #pragma unroll
            for (int j = 0; j < 4; ++j) {
                w0[j] = bf_bits(a0[j]); w0[j + 4] = bf_bits(a1[j]);
                w1[j] = bf_bits(a2[j]); w1[j + 4] = bf_bits(a3[j]);
            }
            *(short8*)&An[ar * 32 + ac]     = w0;
            *(short8*)&An[ar * 32 + ac + 8] = w1;
            // DMA B(next)
            const int kn = (s + 1) * 32;
            #pragma unroll
            for (int j = 0; j < 7; ++j)
                async16(bgp + j * 16 * DDIM + kn, Bn + (wid * 7 + j) * 16 * 32);
            // prefetch a-regs for k=(s+2)*32
            if (s + 2 < NSTEP) {              // uniform
                const int k2 = (s + 2) * 32;
                a0 = *(const f32x4*)(agp + k2);
                a1 = *(const f32x4*)(agp + k2 + 4);
                a2 = *(const f32x4*)(agp + k2 + 8);
                a3 = *(const f32x4*)(agp + k2 + 12);
            }
        }

        short8 af[8], bfr[7];
        #pragma unroll
        for (int mi = 0; mi < 8; ++mi)
            af[mi] = *(const short8*)&Ac[(mi * 16 + m_) * 32 + kq * 8];
        #pragma unroll
        for (int ni = 0; ni < 7; ++ni)
            bfr[ni] = *(const short8*)&Bc[(wid * 112 + ni * 16 + m_) * 32 + kq * 8];

        #pragma unroll
        for (int mi = 0; mi < 8; ++mi)
            #pragma unroll
            for (int ni = 0; ni < 7; ++ni)
                acc[mi][ni] = __builtin_amdgcn_mfma_f32_16x16x32_bf16(
                    af[mi], bfr[ni], acc[mi][ni], 0, 0, 0);

        __syncthreads();   // cur fully read; next buffers + vmem drained
    }

    // ---- epilogue: 4 stages of 32 rows; LDS bounce -> coalesced f32x4 stores
    float* Cb = (float*)(smem + 16384);       // 32x448 fp32 (aliases B buffers)
    #pragma unroll
    for (int t = 0; t < 4; ++t) {
        #pragma unroll
        for (int mi2 = 0; mi2 < 2; ++mi2) {
            const int mi = t * 2 + mi2;
            #pragma unroll
            for (int ni = 0; ni < 7; ++ni) {
                const int col = wid * 112 + ni * 16 + m_;
                #pragma unroll
                for (int r = 0; r < 4; ++r)
                    Cb[(mi2 * 16 + kq * 4 + r) * DDIM + col] = acc[mi][ni][r];
            }
        }
        __syncthreads();
        float* dst = out + (row0 + t * 32) * DDIM;    // 32x448 contiguous
        #pragma unroll
        for (int j = 0; j < 14; ++j)
            ((f32x4*)dst)[j * 256 + tid] = ((const f32x4*)Cb)[j * 256 + tid];
        __syncthreads();   // before next stage overwrites Cb
    }
}

// ---------------------------------------------------------------------------
extern "C" void kernel_launch(void* const* d_in, const int* in_sizes, int n_in,
                              void* d_out, int out_size, void* d_ws, size_t ws_size,
                              hipStream_t stream) {
    const float* x  = (const float*)d_in[0];
    const float* Wq = (const float*)d_in[1];
    const float* Wk = (const float*)d_in[2];
    const float* Wv = (const float*)d_in[3];
    const float* Wo = (const float*)d_in[4];
    const float* Ad = (const float*)d_in[5];
    const float* Bd = (const float*)d_in[6];
    const float* Cd = (const float*)d_in[7];

    bf16*  WcT = (bf16*)d_ws;                      // 448*448*2 = 392 KiB scratch
    float* out = (float*)d_out;

    const int M = in_sizes[0] / DDIM;              // 32768

    prep_wc<<<dim3(7, 7), 256, 0, stream>>>(Wq, Wk, Wv, Wo, Ad, Bd, Cd, WcT);
    gemm_xwc<<<M / 128, 256, 0, stream>>>(x, WcT, out);
}